// Round 10
// baseline (505.560 us; speedup 1.0000x reference)
//
#include <hip/hip_runtime.h>
#include <hip/hip_cooperative_groups.h>
#include <cmath>
#include <stdint.h>

// ---------------------------------------------------------------------------
// AttentionLayer: att = softmax((q@W1+b1) @ (k@W2+b2)^T / sqrt(Sk)) @ v
// B=4, SQ=SK=2048, D=UNITS=1024, fp32 in/out, bf16 MFMA internally.
// R14: single cooperative mega-kernel (512 blocks x 512 thr, 2/CU
//      guaranteed by launch_bounds(512,4) + 48KB LDS):
//        phase0 prep (casts + v/W transpose + rowsum zero)  -> grid.sync
//        phase1 l1l2  (verified 256x128 engine, 512 blocks) -> grid.sync
//        phase2 score (verified 256x128 engine, 512 blocks) -> grid.sync
//        phase3 att   (128x128 @ 512 thr, 8 waves 4Mx2N)
//      Removes 3 inter-dispatch gaps (~60-85 us measured wall-GPU slack).
//      Fallback (coop unsupported / ws too small): verified R9 4-kernel path.
// ---------------------------------------------------------------------------

namespace cg = cooperative_groups;

typedef short short8 __attribute__((ext_vector_type(8)));
typedef float f32x4 __attribute__((ext_vector_type(4)));
typedef __bf16 bf16x8 __attribute__((ext_vector_type(8)));

typedef __attribute__((address_space(3))) void lds_void;
typedef __attribute__((address_space(1))) void gbl_void;

__device__ __forceinline__ unsigned short f2b(float x) {
    unsigned u = __builtin_bit_cast(unsigned, x);
    u += 0x7fffu + ((u >> 16) & 1u);
    return (unsigned short)(u >> 16);
}

__device__ __forceinline__ void load16_to_lds(const unsigned short* g,
                                              unsigned short* l) {
    __builtin_amdgcn_global_load_lds((gbl_void*)g, (lds_void*)l, 16, 0, 0);
}

// ---------------------------------------------------------------------------
// Shared GEMM phase: 256x128 tile, BK=64, 512 thr = 8 waves (4Mx2N).
// Verified engine (R8-R13). MODE 0: bf16 +bias; MODE 1: exp + rowsum atomics.
// ---------------------------------------------------------------------------
template <int MODE>
__device__ __forceinline__ void gemm256_phase(
        unsigned short* As, unsigned short* Bs,
        const unsigned short* A, const unsigned short* Bt,
        const float* bias0, const float* bias1,
        float* rowsum, void* Cout,
        int M, int N, int K, float scale,
        long sA, long sB, long sC,
        int bx, int by, int bz, int t) {
    A  += (long)bz * sA;
    Bt += (long)bz * sB;

    const int lane = t & 63;
    const int wave = t >> 6;
    const int wm = wave >> 1, wn = wave & 1;
    const int row0 = by * 256;
    const int col0 = bx * 128;

    const int rS = lane >> 3;
    const int kOffS = ((lane & 7) ^ rS) * 8;
    const unsigned short* gA[4];
    unsigned short* lA[4];
    const unsigned short* gB[2];
    unsigned short* lB[2];
#pragma unroll
    for (int i = 0; i < 4; i++) {
        const int rowl = wave * 32 + i * 8;
        gA[i] = A + (long)(row0 + rowl + rS) * K + kOffS;
        lA[i] = As + rowl * 64;
    }
#pragma unroll
    for (int i = 0; i < 2; i++) {
        const int rowl = wave * 16 + i * 8;
        gB[i] = Bt + (long)(col0 + rowl + rS) * K + kOffS;
        lB[i] = Bs + rowl * 64;
    }

    const int lr = lane & 15;
    const int quad = lane >> 4;
    const int pc0 = (quad ^ (lr & 7)) * 8;
    const int pc1 = ((4 + quad) ^ (lr & 7)) * 8;

    f32x4 acc[4][4];
#pragma unroll
    for (int i = 0; i < 4; i++)
#pragma unroll
        for (int j = 0; j < 4; j++) acc[i][j] = f32x4{0.f, 0.f, 0.f, 0.f};

    for (int k0 = 0; k0 < K; k0 += 64) {
#pragma unroll
        for (int i = 0; i < 4; i++) load16_to_lds(gA[i] + k0, lA[i]);
#pragma unroll
        for (int i = 0; i < 2; i++) load16_to_lds(gB[i] + k0, lB[i]);
        __syncthreads();

#pragma unroll
        for (int ks = 0; ks < 2; ks++) {
            const int pc = ks ? pc1 : pc0;
            bf16x8 a[4], b[4];
#pragma unroll
            for (int i = 0; i < 4; i++) {
                a[i] = __builtin_bit_cast(bf16x8,
                    *(const short8*)(As + (wm * 64 + i * 16 + lr) * 64 + pc));
                b[i] = __builtin_bit_cast(bf16x8,
                    *(const short8*)(Bs + (wn * 64 + i * 16 + lr) * 64 + pc));
            }
#pragma unroll
            for (int i = 0; i < 4; i++)
#pragma unroll
                for (int j = 0; j < 4; j++)
                    acc[i][j] = __builtin_amdgcn_mfma_f32_16x16x32_bf16(
                        a[i], b[j], acc[i][j], 0, 0, 0);
        }
        __syncthreads();
    }

    const long cbase = (long)bz * sC;

    if (MODE == 0) {
        const float* bp = (bz && bias1) ? bias1 : bias0;
#pragma unroll
        for (int j = 0; j < 4; j++) {
            const int gcol = col0 + wn * 64 + j * 16 + lr;
            const float bv = bp[gcol];
#pragma unroll
            for (int i = 0; i < 4; i++) {
                const int growb = row0 + wm * 64 + i * 16 + quad * 4;
#pragma unroll
                for (int r = 0; r < 4; r++) {
                    float val = acc[i][j][r] * scale + bv;
                    ((unsigned short*)Cout)[cbase + (long)(growb + r) * N + gcol] = f2b(val);
                }
            }
        }
    } else {
        float psum[4][4];
#pragma unroll
        for (int i = 0; i < 4; i++)
#pragma unroll
            for (int r = 0; r < 4; r++) psum[i][r] = 0.f;
#pragma unroll
        for (int j = 0; j < 4; j++) {
            const int gcol = col0 + wn * 64 + j * 16 + lr;
#pragma unroll
            for (int i = 0; i < 4; i++) {
                const int growb = row0 + wm * 64 + i * 16 + quad * 4;
#pragma unroll
                for (int r = 0; r < 4; r++) {
                    float e = __expf(acc[i][j][r] * scale);
                    psum[i][r] += e;
                    ((unsigned short*)Cout)[cbase + (long)(growb + r) * N + gcol] = f2b(e);
                }
            }
        }
#pragma unroll
        for (int i = 0; i < 4; i++)
#pragma unroll
            for (int r = 0; r < 4; r++) {
                float s = psum[i][r];
                s += __shfl_xor(s, 1);
                s += __shfl_xor(s, 2);
                s += __shfl_xor(s, 4);
                s += __shfl_xor(s, 8);
                if (lr == 0) {
                    const int grow = row0 + wm * 64 + i * 16 + quad * 4 + r;
                    atomicAdd(rowsum + (long)bz * M + grow, s);
                }
            }
    }
}

// ---------------------------------------------------------------------------
// att phase for the mega kernel: 128x128 tile @ 512 thr, 8 waves (4Mx2N),
// per-wave 32x64 output (acc[2][4]).  Same staging/swizzle algebra as the
// verified engines (all row strides multiples of 8 -> row&7 == lr&7 / rS).
// ---------------------------------------------------------------------------
__device__ __forceinline__ void att512_phase(
        unsigned short* As, unsigned short* Bs,
        const unsigned short* A, const unsigned short* Bt,
        const float* rowsum, float* out,
        int bx, int by, int bz, int t) {
    const int M = 2048, N = 1024, K = 2048;
    const long sA = (long)M * K, sB = (long)N * K, sC = (long)M * N;
    const unsigned short* Ab  = A  + (long)bz * sA;
    const unsigned short* Btb = Bt + (long)bz * sB;

    const int lane = t & 63;
    const int w = t >> 6;
    const int wm = w >> 1, wn = w & 1;     // 4M x 2N
    const int row0 = by * 128;
    const int col0 = bx * 128;

    const int rS = lane >> 3;
    const int kOffS = ((lane & 7) ^ rS) * 8;
    const unsigned short* gA[2];
    unsigned short* lA[2];
    const unsigned short* gB[2];
    unsigned short* lB[2];
#pragma unroll
    for (int i = 0; i < 2; i++) {
        const int rowl = w * 16 + i * 8;
        gA[i] = Ab  + (long)(row0 + rowl + rS) * K + kOffS;
        lA[i] = As + rowl * 64;
        gB[i] = Btb + (long)(col0 + rowl + rS) * K + kOffS;
        lB[i] = Bs + rowl * 64;
    }

    const int lr = lane & 15;
    const int quad = lane >> 4;
    const int pc0 = (quad ^ (lr & 7)) * 8;
    const int pc1 = ((4 + quad) ^ (lr & 7)) * 8;

    f32x4 acc[2][4];
#pragma unroll
    for (int i = 0; i < 2; i++)
#pragma unroll
        for (int j = 0; j < 4; j++) acc[i][j] = f32x4{0.f, 0.f, 0.f, 0.f};

    for (int k0 = 0; k0 < K; k0 += 64) {
#pragma unroll
        for (int i = 0; i < 2; i++) {
            load16_to_lds(gA[i] + k0, lA[i]);
            load16_to_lds(gB[i] + k0, lB[i]);
        }
        __syncthreads();
#pragma unroll
        for (int ks = 0; ks < 2; ks++) {
            const int pc = ks ? pc1 : pc0;
            bf16x8 a[2], b[4];
#pragma unroll
            for (int i = 0; i < 2; i++)
                a[i] = __builtin_bit_cast(bf16x8,
                    *(const short8*)(As + (wm * 32 + i * 16 + lr) * 64 + pc));
#pragma unroll
            for (int j = 0; j < 4; j++)
                b[j] = __builtin_bit_cast(bf16x8,
                    *(const short8*)(Bs + (wn * 64 + j * 16 + lr) * 64 + pc));
#pragma unroll
            for (int i = 0; i < 2; i++)
#pragma unroll
                for (int j = 0; j < 4; j++)
                    acc[i][j] = __builtin_amdgcn_mfma_f32_16x16x32_bf16(
                        a[i], b[j], acc[i][j], 0, 0, 0);
        }
        __syncthreads();
    }

    const long cbase = (long)bz * sC;
#pragma unroll
    for (int i = 0; i < 2; i++) {
        const int growb = row0 + wm * 32 + i * 16 + quad * 4;
#pragma unroll
        for (int r = 0; r < 4; r++) {
            const float inv = 1.0f / rowsum[(long)bz * M + growb + r];
#pragma unroll
            for (int j = 0; j < 4; j++) {
                const int gcol = col0 + wn * 64 + j * 16 + lr;
                out[cbase + (long)(growb + r) * N + gcol] = acc[i][j][r] * inv;
            }
        }
    }
}

// ---------------------------------------------------------------------------
// Mega kernel: all 4 stages with grid-wide syncs. 512 blocks x 512 thr.
// ---------------------------------------------------------------------------
struct MegaArgs {
    const float *q, *k, *v, *W1, *W2, *b1, *b2;
    unsigned short *qbf, *kbf, *vT, *W1t, *W2t, *l1, *l2, *sc;
    float *rowsum, *out;
    float invs;
};

__global__ __launch_bounds__(512, 4) void mega_kernel(MegaArgs a) {
    __shared__ __align__(16) unsigned short As[256 * 64];  // 32 KB
    __shared__ __align__(16) unsigned short Bs[128 * 64];  // 16 KB

    const int bid = blockIdx.x;
    const int t = threadIdx.x;
    // XCD-contiguous swizzle of the 512 linear blocks (8 XCDs x 64)
    const int swz = (bid & 7) * 64 + (bid >> 3);

    // ================= phase 0: prep =================
    // q/k casts: 8M elems each, 4 grid passes each, float4x2 per thread.
#pragma unroll
    for (int it = 0; it < 4; ++it) {
        const long i = ((long)(it * 512 + bid) * 512 + t) * 8;
        float4 x = *(const float4*)(a.q + i);
        float4 y = *(const float4*)(a.q + i + 4);
        union { short8 v8; unsigned short u[8]; } r;
        r.u[0] = f2b(x.x); r.u[1] = f2b(x.y); r.u[2] = f2b(x.z); r.u[3] = f2b(x.w);
        r.u[4] = f2b(y.x); r.u[5] = f2b(y.y); r.u[6] = f2b(y.z); r.u[7] = f2b(y.w);
        *(short8*)(a.qbf + i) = r.v8;
    }
#pragma unroll
    for (int it = 0; it < 4; ++it) {
        const long i = ((long)(it * 512 + bid) * 512 + t) * 8;
        float4 x = *(const float4*)(a.k + i);
        float4 y = *(const float4*)(a.k + i + 4);
        union { short8 v8; unsigned short u[8]; } r;
        r.u[0] = f2b(x.x); r.u[1] = f2b(x.y); r.u[2] = f2b(x.z); r.u[3] = f2b(x.w);
        r.u[4] = f2b(y.x); r.u[5] = f2b(y.y); r.u[6] = f2b(y.z); r.u[7] = f2b(y.w);
        *(short8*)(a.kbf + i) = r.v8;
    }
    // rowsum zero
    if (bid < 16) a.rowsum[bid * 512 + t] = 0.f;

    // transposes: 2048 v-tiles (64x64) + 512 W-tiles; 2 tiles per block-pass
    {
        const int half = t >> 8, st = t & 255;
        unsigned short* tile = As + half * 8192;   // 64*65 = 4160 used
        for (int p = 0; p < 3; ++p) {
            __syncthreads();
            const int id = p * 1024 + bid * 2 + half;
            const float* in = nullptr;
            unsigned short* outp = nullptr;
            int R = 0, C = 0, rt = 0, ct = 0;
            bool active = false;
            if (id < 2048) {
                const int batch = id >> 9, ti = id & 511;
                in = a.v + (long)batch * 2048 * 1024;
                outp = a.vT + (long)batch * 1024 * 2048;
                R = 2048; C = 1024;
                rt = (ti >> 4) * 64; ct = (ti & 15) * 64;
                active = true;
            } else {
                const int wdx = id - 2048;
                if (wdx < 512) {
                    in = (wdx < 256) ? a.W1 : a.W2;
                    outp = (wdx < 256) ? a.W1t : a.W2t;
                    const int ti = wdx & 255;
                    R = 1024; C = 1024;
                    rt = (ti >> 4) * 64; ct = (ti & 15) * 64;
                    active = true;
                }
            }
            if (active) {
                const int rr = st >> 2, cb = (st & 3) * 16;
                const float* src = in + (long)(rt + rr) * C + ct + cb;
                unsigned short* trow = tile + rr * 65 + cb;
#pragma unroll
                for (int u = 0; u < 4; u++) {
                    float4 x = *(const float4*)(src + 4 * u);
                    trow[4 * u + 0] = f2b(x.x);
                    trow[4 * u + 1] = f2b(x.y);
                    trow[4 * u + 2] = f2b(x.z);
                    trow[4 * u + 3] = f2b(x.w);
                }
            }
            __syncthreads();
            if (active) {
                const int cc = st >> 2, rb = (st & 3) * 16;
                unsigned short* dst = outp + (long)(ct + cc) * R + rt + rb;
#pragma unroll
                for (int u = 0; u < 2; u++) {
                    union { short8 v8; unsigned short us[8]; } o;
#pragma unroll
                    for (int e = 0; e < 8; e++)
                        o.us[e] = tile[(rb + 8 * u + e) * 65 + cc];
                    *(short8*)(dst + 8 * u) = o.v8;
                }
            }
        }
    }

    cg::this_grid().sync();

    // ================= phase 1: l1l2 =================
    {
        const int bx = swz & 7, by = (swz >> 3) & 31, bz = swz >> 8;
        gemm256_phase<0>(As, Bs, a.qbf, a.W1t, a.b1, a.b2, nullptr, a.l1,
                         8192, 1024, 1024, 1.0f,
                         (long)8 * 1024 * 1024, (long)1024 * 1024,
                         (long)8 * 1024 * 1024, bx, by, bz, t);
    }
    cg::this_grid().sync();

    // ================= phase 2: score =================
    {
        const int bx = swz & 15, by = (swz >> 4) & 7, bz = swz >> 7;
        gemm256_phase<1>(As, Bs, a.l1, a.l2, nullptr, nullptr, a.rowsum, a.sc,
                         2048, 2048, 1024, a.invs,
                         (long)2048 * 1024, (long)2048 * 1024,
                         (long)2048 * 2048, bx, by, bz, t);
    }
    cg::this_grid().sync();

    // ================= phase 3: att =================
    {
        const int bx = swz & 7, by = (swz >> 3) & 15, bz = swz >> 7;
        att512_phase(As, Bs, a.sc, a.vT, a.rowsum, a.out, bx, by, bz, t);
    }
}

// ---------------------------------------------------------------------------
// Fallback path: verified R9 4-kernel pipeline.
// ---------------------------------------------------------------------------
__global__ void prep_kernel(const float* __restrict__ q,
                            const float* __restrict__ k,
                            const float* __restrict__ v,
                            const float* __restrict__ W1,
                            const float* __restrict__ W2,
                            unsigned short* __restrict__ qbf,
                            unsigned short* __restrict__ kbf,
                            unsigned short* __restrict__ vT,
                            unsigned short* __restrict__ W1t,
                            unsigned short* __restrict__ W2t,
                            float* __restrict__ rs) {
    const int bz = blockIdx.z;
    const int t = threadIdx.x;

    if (bz >= 6) {
        const float* in = (bz < 8) ? q : k;
        unsigned short* out = (bz < 8) ? qbf : kbf;
        const long zi = (bz - 6) & 1;
        const long fb = zi * 2048 + blockIdx.y * 64 + blockIdx.x;
        const long i = (fb * 256 + t) * 8;
        float4 a = *(const float4*)(in + i);
        float4 b = *(const float4*)(in + i + 4);
        union { short8 v8; unsigned short u[8]; } r;
        r.u[0] = f2b(a.x); r.u[1] = f2b(a.y); r.u[2] = f2b(a.z); r.u[3] = f2b(a.w);
        r.u[4] = f2b(b.x); r.u[5] = f2b(b.y); r.u[6] = f2b(b.z); r.u[7] = f2b(b.w);
        *(short8*)(out + i) = r.v8;
        return;
    }

    const int tid2 = blockIdx.y * 64 + blockIdx.x;
    if (bz == 4 && tid2 >= 256 && tid2 < 288) {
        if (rs) rs[(tid2 - 256) * 256 + t] = 0.f;
        return;
    }

    __shared__ float tile[64][65];
    const float* in;
    unsigned short* out;
    int R, C;
    if (bz < 4) {
        R = 2048; C = 1024;
        if (tid2 >= 512) return;
        in = v + (long)bz * R * C;
        out = vT + (long)bz * R * C;
    } else {
        R = 1024; C = 1024;
        if (tid2 >= 256) return;
        in = (bz == 4) ? W1 : W2;
        out = (bz == 4) ? W1t : W2t;
    }
    const int rt = (tid2 >> 4) * 64;
    const int ct = (tid2 & 15) * 64;
    {
        const int rr = t >> 2, cb = (t & 3) * 16;
        const float* src = in + (long)(rt + rr) * C + ct + cb;
#pragma unroll
        for (int u = 0; u < 4; u++) {
            float4 x = *(const float4*)(src + 4 * u);
            tile[rr][cb + 4 * u + 0] = x.x;
            tile[rr][cb + 4 * u + 1] = x.y;
            tile[rr][cb + 4 * u + 2] = x.z;
            tile[rr][cb + 4 * u + 3] = x.w;
        }
    }
    __syncthreads();
    {
        const int cc = t >> 2, rb = (t & 3) * 16;
        unsigned short* dst = out + (long)(ct + cc) * R + rt + rb;
#pragma unroll
        for (int u = 0; u < 2; u++) {
            union { short8 v8; unsigned short us[8]; } o;
#pragma unroll
            for (int e = 0; e < 8; e++) o.us[e] = f2b(tile[rb + 8 * u + e][cc]);
            *(short8*)(dst + 8 * u) = o.v8;
        }
    }
}

template <int MODE>
__global__ __launch_bounds__(512, 4) void gemm256_kernel(
                               const unsigned short* A,
                               const unsigned short* Bt,
                               const float* bias0, const float* bias1,
                               float* rowsum, void* Cout,
                               int M, int N, int K, float scale,
                               long sA, long sB, long sC) {
    __shared__ __align__(16) unsigned short As[256 * 64];
    __shared__ __align__(16) unsigned short Bs[128 * 64];
    int bx, by, bz;
    {
        const int nx = gridDim.x;
        const int Rt = gridDim.y * gridDim.z;
        if ((Rt & 7) == 0) {
            int flat = ((int)blockIdx.z * gridDim.y + blockIdx.y) * nx + blockIdx.x;
            int rpx = Rt >> 3;
            int c = flat & 7;
            int j = flat >> 3;
            bx = j / rpx;
            int yg = c * rpx + (j - bx * rpx);
            bz = yg / gridDim.y;
            by = yg - bz * gridDim.y;
        } else {
            bx = blockIdx.x; by = blockIdx.y; bz = blockIdx.z;
        }
    }
    gemm256_phase<MODE>(As, Bs, A, Bt, bias0, bias1, rowsum, Cout,
                        M, N, K, scale, sA, sB, sC, bx, by, bz,
                        (int)threadIdx.x);
}

template <int MODE>
__global__ void gemm128_kernel(const unsigned short* __restrict__ A,
                               const unsigned short* __restrict__ Bt,
                               float* __restrict__ rowsum,
                               void* __restrict__ Cout,
                               int M, int N, int K,
                               long sA, long sB, long sC) {
    __shared__ __align__(16) unsigned short As[128 * 64];
    __shared__ __align__(16) unsigned short Bs[128 * 64];
    int bx, by, bz;
    {
        const int nx = gridDim.x;
        const int Rt = gridDim.y * gridDim.z;
        if ((Rt & 7) == 0) {
            int flat = ((int)blockIdx.z * gridDim.y + blockIdx.y) * nx + blockIdx.x;
            int rpx = Rt >> 3;
            int c = flat & 7;
            int j = flat >> 3;
            bx = j / rpx;
            int yg = c * rpx + (j - bx * rpx);
            bz = yg / gridDim.y;
            by = yg - bz * gridDim.y;
        } else {
            bx = blockIdx.x; by = blockIdx.y; bz = blockIdx.z;
        }
    }

    A  += (long)bz * sA;
    Bt += (long)bz * sB;
    const int t = threadIdx.x;
    const int lane = t & 63;
    const int wave = t >> 6;
    const int wm = wave >> 1, wn = wave & 1;
    const int row0 = by * 128;
    const int col0 = bx * 128;

    const int rS = lane >> 3;
    const int kOffS = ((lane & 7) ^ rS) * 8;
    const unsigned short* gA[4];
    const unsigned short* gB[4];
    unsigned short* lA[4];
    unsigned short* lB[4];
#pragma unroll
    for (int i = 0; i < 4; i++) {
        const int rowl = i * 32 + wave * 8 + rS;
        const int ldsrow = i * 32 + wave * 8;
        gA[i] = A  + (long)(row0 + rowl) * K + kOffS;
        gB[i] = Bt + (long)(col0 + rowl) * K + kOffS;
        lA[i] = As + ldsrow * 64;
        lB[i] = Bs + ldsrow * 64;
    }
    const int lr = lane & 15;
    const int quad = lane >> 4;
    const int pc0 = (quad ^ (lr & 7)) * 8;
    const int pc1 = ((4 + quad) ^ (lr & 7)) * 8;

    f32x4 acc[4][4];
#pragma unroll
    for (int i = 0; i < 4; i++)
#pragma unroll
        for (int j = 0; j < 4; j++) acc[i][j] = f32x4{0.f, 0.f, 0.f, 0.f};

    for (int k0 = 0; k0 < K; k0 += 64) {
#pragma unroll
        for (int i = 0; i < 4; i++) {
            load16_to_lds(gA[i] + k0, lA[i]);
            load16_to_lds(gB[i] + k0, lB[i]);
        }
        __syncthreads();
#pragma unroll
        for (int ks = 0; ks < 2; ks++) {
            const int pc = ks ? pc1 : pc0;
            bf16x8 a[4], b[4];
#pragma unroll
            for (int i = 0; i < 4; i++) {
                a[i] = __builtin_bit_cast(bf16x8,
                    *(const short8*)(As + (wm * 64 + i * 16 + lr) * 64 + pc));
                b[i] = __builtin_bit_cast(bf16x8,
                    *(const short8*)(Bs + (wn * 64 + i * 16 + lr) * 64 + pc));
            }
#pragma unroll
            for (int i = 0; i < 4; i++)
#pragma unroll
                for (int j = 0; j < 4; j++)
                    acc[i][j] = __builtin_amdgcn_mfma_f32_16x16x32_bf16(
                        a[i], b[j], acc[i][j], 0, 0, 0);
        }
        __syncthreads();
    }

    const long cbase = (long)bz * sC;
    if (MODE == 2) {
#pragma unroll
        for (int i = 0; i < 4; i++) {
            const int growb = row0 + wm * 64 + i * 16 + quad * 4;
#pragma unroll
            for (int r = 0; r < 4; r++) {
                const float inv = 1.0f / rowsum[(long)bz * M + growb + r];
#pragma unroll
                for (int j = 0; j < 4; j++) {
                    const int gcol = col0 + wn * 64 + j * 16 + lr;
                    ((float*)Cout)[cbase + (long)(growb + r) * N + gcol] =
                        acc[i][j][r] * inv;
                }
            }
        }
    }
}

// ---------------------------------------------------------------------------
extern "C" void kernel_launch(void* const* d_in, const int* in_sizes, int n_in,
                              void* d_out, int out_size, void* d_ws, size_t ws_size,
                              hipStream_t stream) {
    const float* q   = (const float*)d_in[0];
    const float* k   = (const float*)d_in[1];
    const float* v   = (const float*)d_in[2];
    const float* W1w = (const float*)d_in[3];
    const float* W1b = (const float*)d_in[4];
    const float* W2w = (const float*)d_in[5];
    const float* W2b = (const float*)d_in[6];
    float* out = (float*)d_out;

    const int B = 4, SQ = 2048, SK = 2048, D = 1024, U = 1024;
    char* ws = (char*)d_ws;
    const size_t MB = 1024 * 1024;
    unsigned short* qbf = (unsigned short*)(ws + 0);        // 16 MB
    unsigned short* kbf = (unsigned short*)(ws + 16 * MB);  // 16 MB
    unsigned short* vT  = (unsigned short*)(ws + 32 * MB);  // 16 MB [B][D][SK]
    unsigned short* W1t = (unsigned short*)(ws + 48 * MB);  // 2 MB  [U][D]
    unsigned short* W2t = (unsigned short*)(ws + 50 * MB);  // 2 MB
    unsigned short* l1  = (unsigned short*)(ws + 52 * MB);  // 16 MB [B*SQ][U]
    unsigned short* l2  = (unsigned short*)(ws + 68 * MB);  // 16 MB
    unsigned short* sc  = (unsigned short*)(ws + 0);        // 32 MB (over qbf/kbf)
    const float invs = 1.0f / sqrtf((float)SK);

    // cooperative-launch support check (host attribute query; capture-safe)
    static int coop_support = -1;
    if (coop_support < 0) {
        int dev = 0, val = 0;
        (void)hipGetDevice(&dev);
        if (hipDeviceGetAttribute(&val, hipDeviceAttributeCooperativeLaunch,
                                  dev) != hipSuccess) val = 0;
        coop_support = val;
    }

    if (coop_support && ws_size >= 85 * MB) {
        float* rowsum = (float*)(ws + 84 * MB);
        MegaArgs margs = { q, k, v, W1w, W2w, W1b, W2b,
                           qbf, kbf, vT, W1t, W2t, l1, l2, sc,
                           rowsum, out, invs };
        void* kargs[] = { (void*)&margs };
        hipError_t e = hipLaunchCooperativeKernel(
            (const void*)mega_kernel, dim3(512), dim3(512), kargs, 0, stream);
        if (e == hipSuccess) return;
        (void)hipGetLastError();   // clear, fall through to 4-kernel path
    }

    // ---- fallback: verified R9 pipeline ----
    float* rowsum;
    bool prep_zeroes_rowsum;
    if (ws_size >= 85 * MB) {
        rowsum = (float*)(ws + 84 * MB);
        prep_zeroes_rowsum = true;
    } else {
        rowsum = (float*)(ws + 50 * MB);
        prep_zeroes_rowsum = false;
    }

    prep_kernel<<<dim3(64, 32, 10), 256, 0, stream>>>(
        q, k, v, W1w, W2w, qbf, kbf, vT, W1t, W2t,
        prep_zeroes_rowsum ? rowsum : nullptr);
    gemm256_kernel<0><<<dim3(U / 128, (B * SQ) / 256, 2), 512, 0, stream>>>(
        qbf, W1t, W1b, W2b, nullptr, l1, B * SQ, U, D, 1.0f,
        (long)8 * 1024 * 1024, (long)1024 * 1024, (long)8 * 1024 * 1024);
    if (!prep_zeroes_rowsum)
        hipMemsetAsync(rowsum, 0, (size_t)B * SQ * sizeof(float), stream);
    gemm256_kernel<1><<<dim3(SK / 128, SQ / 256, B), 512, 0, stream>>>(
        l1, l2, nullptr, nullptr, rowsum, sc, SQ, SK, U, invs,
        (long)SQ * U, (long)SK * U, (long)SQ * SK);
    gemm128_kernel<2><<<dim3(D / 128, SQ / 128, B), 256, 0, stream>>>(
        sc, vT, rowsum, out, SQ, D, SK,
        (long)SQ * SK, (long)D * SK, (long)SQ * D);
}

// Round 11
// 368.279 us; speedup vs baseline: 1.3728x; 1.3728x over previous
//
#include <hip/hip_runtime.h>
#include <cmath>
#include <stdint.h>

// ---------------------------------------------------------------------------
// AttentionLayer: att = softmax((q@W1+b1) @ (k@W2+b2)^T / sqrt(Sk)) @ v
// B=4, SQ=SK=2048, D=UNITS=1024, fp32 in/out, bf16 MFMA internally.
// R15: R10 base (best verified 261.7us) + T14 async-STAGE split on the
//      CASTA l1l2 staging: issue tile k0+64's 8 float4 loads BEFORE the
//      __syncthreads (an IR-level memory fence the scheduler cannot sink
//      loads past -- unlike R11/R12's failed pins), convert+ds_write them
//      one iteration later. Staging load latency retires at the barrier,
//      hidden by the co-resident block's MFMA (m114/m249 mechanism).
//      prep / score / att byte-frozen from R10.
// ---------------------------------------------------------------------------

typedef short short8 __attribute__((ext_vector_type(8)));
typedef float f32x4 __attribute__((ext_vector_type(4)));
typedef __bf16 bf16x8 __attribute__((ext_vector_type(8)));
typedef unsigned int u32x4 __attribute__((ext_vector_type(4)));

typedef __attribute__((address_space(3))) void lds_void;
typedef __attribute__((address_space(1))) void gbl_void;

__device__ __forceinline__ unsigned short f2b(float x) {
    unsigned u = __builtin_bit_cast(unsigned, x);
    u += 0x7fffu + ((u >> 16) & 1u);
    return (unsigned short)(u >> 16);
}

// ---------------------------------------------------------------------------
// Slim prep: z = 0..3 v-batch transpose (64x64 tiles), z=4 W1 transpose
// (+ rowsum zero stowaway), z=5 W2 transpose.  grid (64, 8, 6) x 256 thr.
// ---------------------------------------------------------------------------
__global__ void prep_kernel(const float* __restrict__ v,
                            const float* __restrict__ W1,
                            const float* __restrict__ W2,
                            unsigned short* __restrict__ vT,
                            unsigned short* __restrict__ W1t,
                            unsigned short* __restrict__ W2t,
                            float* __restrict__ rs) {
    const int bz = blockIdx.z;
    const int t = threadIdx.x;
    const int tid2 = blockIdx.y * 64 + blockIdx.x;   // 0..511

    // ---- rowsum-zero stowaway: 32 blocks of the z=4 slice ----
    if (bz == 4 && tid2 >= 256 && tid2 < 288) {
        if (rs) rs[(tid2 - 256) * 256 + t] = 0.f;
        return;
    }

    __shared__ float tile[64][65];
    const float* in;
    unsigned short* out;
    int R, C;
    if (bz < 4) {
        R = 2048; C = 1024;                 // v: 32 row-tiles x 16 col-tiles
        in = v + (long)bz * R * C;
        out = vT + (long)bz * R * C;
    } else {
        R = 1024; C = 1024;                 // W: 16 x 16 tiles
        if (tid2 >= 256) return;
        in = (bz == 4) ? W1 : W2;
        out = (bz == 4) ? W1t : W2t;
    }
    const int rt = (tid2 >> 4) * 64;
    const int ct = (tid2 & 15) * 64;

    {
        const int rr = t >> 2;              // 0..63
        const int cb = (t & 3) * 16;        // 0,16,32,48
        const float* src = in + (long)(rt + rr) * C + ct + cb;
#pragma unroll
        for (int u = 0; u < 4; u++) {
            float4 a = *(const float4*)(src + 4 * u);
            tile[rr][cb + 4 * u + 0] = a.x;
            tile[rr][cb + 4 * u + 1] = a.y;
            tile[rr][cb + 4 * u + 2] = a.z;
            tile[rr][cb + 4 * u + 3] = a.w;
        }
    }
    __syncthreads();
    {
        const int cc = t >> 2;              // 0..63
        const int rb = (t & 3) * 16;        // 0,16,32,48
        unsigned short* dst = out + (long)(ct + cc) * R + rt + rb;
#pragma unroll
        for (int u = 0; u < 2; u++) {
            union { short8 v8; unsigned short us[8]; } o;
#pragma unroll
            for (int e = 0; e < 8; e++) o.us[e] = f2b(tile[rb + 8 * u + e][cc]);
            *(short8*)(dst + 8 * u) = o.v8;
        }
    }
}

__device__ __forceinline__ void load16_to_lds(const unsigned short* g,
                                              unsigned short* l) {
    __builtin_amdgcn_global_load_lds((gbl_void*)g, (lds_void*)l, 16, 0, 0);
}

// ---------------------------------------------------------------------------
// 256x128 bf16 GEMM: C[M][N] = A[M][K] * Bt[N][K]^T, BK=64 (48 KB LDS),
// 512 thr = 8 waves (4Mx2N), each wave 4x4 of 16x16x32 MFMA per sub-k.
// LDS XOR swizzle (phys chunk = logical ^ (row&7)); XCD-stripe block remap.
// Single-buffered 2-barrier loop; latency hidden by 2 blocks/CU residency.
// CASTA=1: A is fp32 (Afq bz=0 / Afk bz=1). T14 split staging:
//   iter k0: cvt+ds_write regs loaded LAST iter, then ISSUE k0+64's loads
//   before __syncthreads (fence) -> latency retires at the barrier.
// MODE 0: bf16 out, + bias (bias1 used when bz==1 -- merged l1/l2)
// MODE 1: bf16 out = exp(acc*scale), atomicAdd per-row sums into rowsum
// ---------------------------------------------------------------------------
template <int MODE, int CASTA>
__global__ __launch_bounds__(512, 4) void gemm256_kernel(
                               const unsigned short* __restrict__ A,
                               const unsigned short* __restrict__ Bt,
                               const float* __restrict__ bias0,
                               const float* __restrict__ bias1,
                               float* __restrict__ rowsum,
                               void* __restrict__ Cout,
                               int M, int N, int K,
                               float scale,
                               long sA, long sB, long sC,
                               const float* __restrict__ Afq,
                               const float* __restrict__ Afk) {
    __shared__ __align__(16) unsigned short As[256 * 64];  // 32 KB
    __shared__ __align__(16) unsigned short Bs[128 * 64];  // 16 KB

    // ---- XCD-aware tile remap (bijective) ----
    int bx, by, bz;
    {
        const int nx = gridDim.x;
        const int Rt = gridDim.y * gridDim.z;
        if ((Rt & 7) == 0) {
            int flat = ((int)blockIdx.z * gridDim.y + blockIdx.y) * nx + blockIdx.x;
            int rpx = Rt >> 3;
            int c = flat & 7;
            int j = flat >> 3;
            bx = j / rpx;
            int yg = c * rpx + (j - bx * rpx);
            bz = yg / gridDim.y;
            by = yg - bz * gridDim.y;
        } else {
            bx = blockIdx.x; by = blockIdx.y; bz = blockIdx.z;
        }
    }

    Bt += (long)bz * sB;

    const int t = threadIdx.x;
    const int lane = t & 63;
    const int wave = t >> 6;               // 0..7
    const int wm = wave >> 1, wn = wave & 1;  // 4M x 2N
    const int row0 = by * 256;
    const int col0 = bx * 128;

    // staging: lane l -> row group l>>3 (8 rows/issue), phys chunk l&7;
    // source chunk XOR'd so phys = logical ^ (row&7)
    const int rS = lane >> 3;
    const int kOffS = ((lane & 7) ^ rS) * 8;
    const unsigned short* gA[4];
    const float* fA[4];
    unsigned short* lA[4];
    const unsigned short* gB[2];
    unsigned short* lB[2];
#pragma unroll
    for (int i = 0; i < 4; i++) {
        const int rowl = wave * 32 + i * 8;
        lA[i] = As + rowl * 64;
        if (CASTA) {
            const float* Af = bz ? Afk : Afq;
            fA[i] = Af + (long)(row0 + rowl + rS) * K + kOffS;
        } else {
            gA[i] = A + (long)bz * sA + (long)(row0 + rowl + rS) * K + kOffS;
        }
    }
#pragma unroll
    for (int i = 0; i < 2; i++) {
        const int rowl = wave * 16 + i * 8;
        gB[i] = Bt + (long)(col0 + rowl + rS) * K + kOffS;
        lB[i] = Bs + rowl * 64;
    }

    const int lr = lane & 15;
    const int quad = lane >> 4;
    const int pc0 = (quad ^ (lr & 7)) * 8;
    const int pc1 = ((4 + quad) ^ (lr & 7)) * 8;

    f32x4 acc[4][4];
#pragma unroll
    for (int i = 0; i < 4; i++)
#pragma unroll
        for (int j = 0; j < 4; j++) acc[i][j] = f32x4{0.f, 0.f, 0.f, 0.f};

    // T14 persistent staging regs (CASTA only; DCE'd otherwise)
    float4 x0_0, x1_0, x0_1, x1_1, x0_2, x1_2, x0_3, x1_3;
    if (CASTA) {
        // prologue: load tile k0=0
        x0_0 = *(const float4*)(fA[0]); x1_0 = *(const float4*)(fA[0] + 4);
        x0_1 = *(const float4*)(fA[1]); x1_1 = *(const float4*)(fA[1] + 4);
        x0_2 = *(const float4*)(fA[2]); x1_2 = *(const float4*)(fA[2] + 4);
        x0_3 = *(const float4*)(fA[3]); x1_3 = *(const float4*)(fA[3] + 4);
    }

    for (int k0 = 0; k0 < K; k0 += 64) {
#pragma unroll
        for (int i = 0; i < 2; i++) load16_to_lds(gB[i] + k0, lB[i]);
        if (CASTA) {
            // convert + LDS-write the regs loaded one iteration ago
#define CVT_UNIT(X0, X1, LI) do { \
                unsigned w0_, w1_, w2_, w3_; \
                asm("v_cvt_pk_bf16_f32 %0, %1, %2" : "=v"(w0_) : "v"((X0).x), "v"((X0).y)); \
                asm("v_cvt_pk_bf16_f32 %0, %1, %2" : "=v"(w1_) : "v"((X0).z), "v"((X0).w)); \
                asm("v_cvt_pk_bf16_f32 %0, %1, %2" : "=v"(w2_) : "v"((X1).x), "v"((X1).y)); \
                asm("v_cvt_pk_bf16_f32 %0, %1, %2" : "=v"(w3_) : "v"((X1).z), "v"((X1).w)); \
                *(u32x4*)(lA[LI] + lane * 8) = u32x4{w0_, w1_, w2_, w3_}; \
            } while (0)
            CVT_UNIT(x0_0, x1_0, 0);
            CVT_UNIT(x0_1, x1_1, 1);
            CVT_UNIT(x0_2, x1_2, 2);
            CVT_UNIT(x0_3, x1_3, 3);
#undef CVT_UNIT
            // issue NEXT tile's loads before the barrier (uniform guard);
            // __syncthreads is a memory fence -> loads cannot sink past it,
            // and its vmcnt drain retires them under the co-block's MFMA.
            if (k0 + 64 < K) {
                const float* s0 = fA[0] + k0 + 64;
                const float* s1 = fA[1] + k0 + 64;
                const float* s2 = fA[2] + k0 + 64;
                const float* s3 = fA[3] + k0 + 64;
                x0_0 = *(const float4*)(s0); x1_0 = *(const float4*)(s0 + 4);
                x0_1 = *(const float4*)(s1); x1_1 = *(const float4*)(s1 + 4);
                x0_2 = *(const float4*)(s2); x1_2 = *(const float4*)(s2 + 4);
                x0_3 = *(const float4*)(s3); x1_3 = *(const float4*)(s3 + 4);
            }
        } else {
#pragma unroll
            for (int i = 0; i < 4; i++) load16_to_lds(gA[i] + k0, lA[i]);
        }
        __syncthreads();

#pragma unroll
        for (int ks = 0; ks < 2; ks++) {
            const int pc = ks ? pc1 : pc0;
            bf16x8 a[4], b[4];
#pragma unroll
            for (int i = 0; i < 4; i++) {
                a[i] = __builtin_bit_cast(bf16x8,
                    *(const short8*)(As + (wm * 64 + i * 16 + lr) * 64 + pc));
                b[i] = __builtin_bit_cast(bf16x8,
                    *(const short8*)(Bs + (wn * 64 + i * 16 + lr) * 64 + pc));
            }
#pragma unroll
            for (int i = 0; i < 4; i++)
#pragma unroll
                for (int j = 0; j < 4; j++)
                    acc[i][j] = __builtin_amdgcn_mfma_f32_16x16x32_bf16(
                        a[i], b[j], acc[i][j], 0, 0, 0);
        }
        __syncthreads();
    }

    // ---- epilogue (C/D layout: col = lane&15, row = quad*4 + reg) ----
    const long cbase = (long)bz * sC;

    if (MODE == 0) {
        const float* bp = (bz && bias1) ? bias1 : bias0;
#pragma unroll
        for (int j = 0; j < 4; j++) {
            const int gcol = col0 + wn * 64 + j * 16 + lr;
            const float bv = bp[gcol];
#pragma unroll
            for (int i = 0; i < 4; i++) {
                const int growb = row0 + wm * 64 + i * 16 + quad * 4;
#pragma unroll
                for (int r = 0; r < 4; r++) {
                    float val = acc[i][j][r] * scale + bv;
                    ((unsigned short*)Cout)[cbase + (long)(growb + r) * N + gcol] = f2b(val);
                }
            }
        }
    } else {  // MODE == 1
        float psum[4][4];
#pragma unroll
        for (int i = 0; i < 4; i++)
#pragma unroll
            for (int r = 0; r < 4; r++) psum[i][r] = 0.f;
#pragma unroll
        for (int j = 0; j < 4; j++) {
            const int gcol = col0 + wn * 64 + j * 16 + lr;
#pragma unroll
            for (int i = 0; i < 4; i++) {
                const int growb = row0 + wm * 64 + i * 16 + quad * 4;
#pragma unroll
                for (int r = 0; r < 4; r++) {
                    float e = __expf(acc[i][j][r] * scale);
                    psum[i][r] += e;
                    ((unsigned short*)Cout)[cbase + (long)(growb + r) * N + gcol] = f2b(e);
                }
            }
        }
        // reduce across the 16 lr lanes (xor masks 1,2,4,8 keep quad bits)
#pragma unroll
        for (int i = 0; i < 4; i++)
#pragma unroll
            for (int r = 0; r < 4; r++) {
                float s = psum[i][r];
                s += __shfl_xor(s, 1);
                s += __shfl_xor(s, 2);
                s += __shfl_xor(s, 4);
                s += __shfl_xor(s, 8);
                if (lr == 0) {
                    const int grow = row0 + wm * 64 + i * 16 + quad * 4 + r;
                    atomicAdd(rowsum + (long)bz * M + grow, s);
                }
            }
    }
}

// ---------------------------------------------------------------------------
// Verbatim R4 128x128 engine -- used for the att GEMM (512 blocks = 2/CU).
// ---------------------------------------------------------------------------
template <int MODE>
__global__ void gemm128_kernel(const unsigned short* __restrict__ A,
                               const unsigned short* __restrict__ Bt,
                               float* __restrict__ rowsum,
                               void* __restrict__ Cout,
                               int M, int N, int K,
                               long sA, long sB, long sC) {
    __shared__ __align__(16) unsigned short As[128 * 64];
    __shared__ __align__(16) unsigned short Bs[128 * 64];

    int bx, by, bz;
    {
        const int nx = gridDim.x;
        const int Rt = gridDim.y * gridDim.z;
        if ((Rt & 7) == 0) {
            int flat = ((int)blockIdx.z * gridDim.y + blockIdx.y) * nx + blockIdx.x;
            int rpx = Rt >> 3;
            int c = flat & 7;
            int j = flat >> 3;
            bx = j / rpx;
            int yg = c * rpx + (j - bx * rpx);
            bz = yg / gridDim.y;
            by = yg - bz * gridDim.y;
        } else {
            bx = blockIdx.x; by = blockIdx.y; bz = blockIdx.z;
        }
    }

    A  += (long)bz * sA;
    Bt += (long)bz * sB;

    const int t = threadIdx.x;
    const int lane = t & 63;
    const int wave = t >> 6;
    const int wm = wave >> 1, wn = wave & 1;
    const int row0 = by * 128;
    const int col0 = bx * 128;

    const int rS = lane >> 3;
    const int kOffS = ((lane & 7) ^ rS) * 8;
    const unsigned short* gA[4];
    const unsigned short* gB[4];
    unsigned short* lA[4];
    unsigned short* lB[4];
#pragma unroll
    for (int i = 0; i < 4; i++) {
        const int rowl = i * 32 + wave * 8 + rS;
        const int ldsrow = i * 32 + wave * 8;
        gA[i] = A  + (long)(row0 + rowl) * K + kOffS;
        gB[i] = Bt + (long)(col0 + rowl) * K + kOffS;
        lA[i] = As + ldsrow * 64;
        lB[i] = Bs + ldsrow * 64;
    }

    const int lr = lane & 15;
    const int quad = lane >> 4;
    const int pc0 = (quad ^ (lr & 7)) * 8;
    const int pc1 = ((4 + quad) ^ (lr & 7)) * 8;

    f32x4 acc[4][4];
#pragma unroll
    for (int i = 0; i < 4; i++)
#pragma unroll
        for (int j = 0; j < 4; j++) acc[i][j] = f32x4{0.f, 0.f, 0.f, 0.f};

    for (int k0 = 0; k0 < K; k0 += 64) {
#pragma unroll
        for (int i = 0; i < 4; i++) {
            load16_to_lds(gA[i] + k0, lA[i]);
            load16_to_lds(gB[i] + k0, lB[i]);
        }
        __syncthreads();

#pragma unroll
        for (int ks = 0; ks < 2; ks++) {
            const int pc = ks ? pc1 : pc0;
            bf16x8 a[4], b[4];
#pragma unroll
            for (int i = 0; i < 4; i++) {
                a[i] = __builtin_bit_cast(bf16x8,
                    *(const short8*)(As + (wm * 64 + i * 16 + lr) * 64 + pc));
                b[i] = __builtin_bit_cast(bf16x8,
                    *(const short8*)(Bs + (wn * 64 + i * 16 + lr) * 64 + pc));
            }
#pragma unroll
            for (int i = 0; i < 4; i++)
#pragma unroll
                for (int j = 0; j < 4; j++)
                    acc[i][j] = __builtin_amdgcn_mfma_f32_16x16x32_bf16(
                        a[i], b[j], acc[i][j], 0, 0, 0);
        }
        __syncthreads();
    }

    const long cbase = (long)bz * sC;

    if (MODE == 2) {
#pragma unroll
        for (int i = 0; i < 4; i++) {
            const int growb = row0 + wm * 64 + i * 16 + quad * 4;
#pragma unroll
            for (int r = 0; r < 4; r++) {
                const float inv = 1.0f / rowsum[(long)bz * M + growb + r];
#pragma unroll
                for (int j = 0; j < 4; j++) {
                    const int gcol = col0 + wn * 64 + j * 16 + lr;
                    ((float*)Cout)[cbase + (long)(growb + r) * N + gcol] =
                        acc[i][j][r] * inv;
                }
            }
        }
    }
}

// ---------------------------------------------------------------------------
extern "C" void kernel_launch(void* const* d_in, const int* in_sizes, int n_in,
                              void* d_out, int out_size, void* d_ws, size_t ws_size,
                              hipStream_t stream) {
    const float* q   = (const float*)d_in[0];
    const float* k   = (const float*)d_in[1];
    const float* v   = (const float*)d_in[2];
    const float* W1w = (const float*)d_in[3];
    const float* W1b = (const float*)d_in[4];
    const float* W2w = (const float*)d_in[5];
    const float* W2b = (const float*)d_in[6];
    float* out = (float*)d_out;

    const int B = 4, SQ = 2048, SK = 2048, D = 1024, U = 1024;
    char* ws = (char*)d_ws;
    const size_t MB = 1024 * 1024;
    unsigned short* vT  = (unsigned short*)(ws + 32 * MB);  // 16 MB [B][D][SK]
    unsigned short* W1t = (unsigned short*)(ws + 48 * MB);  // 2 MB  [U][D]
    unsigned short* W2t = (unsigned short*)(ws + 50 * MB);  // 2 MB
    unsigned short* l1  = (unsigned short*)(ws + 52 * MB);  // 16 MB [B*SQ][U]
    unsigned short* l2  = (unsigned short*)(ws + 68 * MB);  // 16 MB
    unsigned short* sc  = (unsigned short*)(ws + 0);        // 32 MB [B][SQ][SK]

    // rowsum: fresh slot at 84 MB, zeroed inside prep (no memset dispatch);
    // fallback: W2t slot + memset between l1l2 and score.
    float* rowsum;
    bool prep_zeroes_rowsum;
    if (ws_size >= 85 * MB) {
        rowsum = (float*)(ws + 84 * MB);
        prep_zeroes_rowsum = true;
    } else {
        rowsum = (float*)(ws + 50 * MB);
        prep_zeroes_rowsum = false;
    }

    // 1: prep (v/W transposes + rowsum zero) -- q/k casts in-GEMM (T14)
    prep_kernel<<<dim3(64, 8, 6), 256, 0, stream>>>(
        v, W1w, W2w, vT, W1t, W2t,
        prep_zeroes_rowsum ? rowsum : nullptr);
    // 2: merged l1 = q@W1+b1 (bz=0), l2 = k@W2+b2 (bz=1); A cast in-flight
    gemm256_kernel<0, 1><<<dim3(U / 128, (B * SQ) / 256, 2), 512, 0, stream>>>(
        nullptr, W1t, W1b, W2b, nullptr, l1, B * SQ, U, D, 1.0f,
        0, (long)1024 * 1024, (long)8 * 1024 * 1024, q, k);
    // 3 (fallback only): zero rowsum in the W2t slot after l1l2 read it
    if (!prep_zeroes_rowsum)
        hipMemsetAsync(rowsum, 0, (size_t)B * SQ * sizeof(float), stream);
    // 4: sc = exp(l1 @ l2^T / sqrt(SK)) bf16 + rowsum atomics
    const float invs = 1.0f / sqrtf((float)SK);
    gemm256_kernel<1, 0><<<dim3(SK / 128, SQ / 256, B), 512, 0, stream>>>(
        l1, l2, nullptr, nullptr, rowsum, sc, SQ, SK, U, invs,
        (long)SQ * U, (long)SK * U, (long)SQ * SK, nullptr, nullptr);
    // 5: att = (sc @ vT^T) / rowsum[row]  (fp32 out) -- proven 128^2 engine
    gemm128_kernel<2><<<dim3(D / 128, SQ / 128, B), 256, 0, stream>>>(
        sc, vT, rowsum, out, SQ, D, SK,
        (long)SQ * SK, (long)D * SK, (long)SQ * D);
}

// Round 12
// 266.750 us; speedup vs baseline: 1.8953x; 1.3806x over previous
//
#include <hip/hip_runtime.h>
#include <cmath>
#include <stdint.h>

// ---------------------------------------------------------------------------
// AttentionLayer: att = softmax((q@W1+b1) @ (k@W2+b2)^T / sqrt(Sk)) @ v
// B=4, SQ=SK=2048, D=UNITS=1024, fp32 in/out, bf16 MFMA internally.
// R16 == R10 (best verified, 261.7 us): q/k cast in-GEMM (CASTA, the
//      plain serialized form -- R11/R12/R15's "fixes" all regressed:
//      compiler either re-serializes or spills; accepted), slim prep
//      (v/W transposes + rowsum zero), score 256x128, att 128^2.
// ---------------------------------------------------------------------------

typedef short short8 __attribute__((ext_vector_type(8)));
typedef float f32x4 __attribute__((ext_vector_type(4)));
typedef __bf16 bf16x8 __attribute__((ext_vector_type(8)));
typedef unsigned int u32x4 __attribute__((ext_vector_type(4)));

typedef __attribute__((address_space(3))) void lds_void;
typedef __attribute__((address_space(1))) void gbl_void;

__device__ __forceinline__ unsigned short f2b(float x) {
    unsigned u = __builtin_bit_cast(unsigned, x);
    u += 0x7fffu + ((u >> 16) & 1u);
    return (unsigned short)(u >> 16);
}

// ---------------------------------------------------------------------------
// Slim prep: z = 0..3 v-batch transpose (64x64 tiles), z=4 W1 transpose
// (+ rowsum zero stowaway), z=5 W2 transpose.  grid (64, 8, 6) x 256 thr.
// ---------------------------------------------------------------------------
__global__ void prep_kernel(const float* __restrict__ v,
                            const float* __restrict__ W1,
                            const float* __restrict__ W2,
                            unsigned short* __restrict__ vT,
                            unsigned short* __restrict__ W1t,
                            unsigned short* __restrict__ W2t,
                            float* __restrict__ rs) {
    const int bz = blockIdx.z;
    const int t = threadIdx.x;
    const int tid2 = blockIdx.y * 64 + blockIdx.x;   // 0..511

    // ---- rowsum-zero stowaway: 32 blocks of the z=4 slice ----
    if (bz == 4 && tid2 >= 256 && tid2 < 288) {
        if (rs) rs[(tid2 - 256) * 256 + t] = 0.f;
        return;
    }

    __shared__ float tile[64][65];
    const float* in;
    unsigned short* out;
    int R, C;
    if (bz < 4) {
        R = 2048; C = 1024;                 // v: 32 row-tiles x 16 col-tiles
        in = v + (long)bz * R * C;
        out = vT + (long)bz * R * C;
    } else {
        R = 1024; C = 1024;                 // W: 16 x 16 tiles
        if (tid2 >= 256) return;
        in = (bz == 4) ? W1 : W2;
        out = (bz == 4) ? W1t : W2t;
    }
    const int rt = (tid2 >> 4) * 64;
    const int ct = (tid2 & 15) * 64;

    {
        const int rr = t >> 2;              // 0..63
        const int cb = (t & 3) * 16;        // 0,16,32,48
        const float* src = in + (long)(rt + rr) * C + ct + cb;
#pragma unroll
        for (int u = 0; u < 4; u++) {
            float4 a = *(const float4*)(src + 4 * u);
            tile[rr][cb + 4 * u + 0] = a.x;
            tile[rr][cb + 4 * u + 1] = a.y;
            tile[rr][cb + 4 * u + 2] = a.z;
            tile[rr][cb + 4 * u + 3] = a.w;
        }
    }
    __syncthreads();
    {
        const int cc = t >> 2;              // 0..63
        const int rb = (t & 3) * 16;        // 0,16,32,48
        unsigned short* dst = out + (long)(ct + cc) * R + rt + rb;
#pragma unroll
        for (int u = 0; u < 2; u++) {
            union { short8 v8; unsigned short us[8]; } o;
#pragma unroll
            for (int e = 0; e < 8; e++) o.us[e] = f2b(tile[rb + 8 * u + e][cc]);
            *(short8*)(dst + 8 * u) = o.v8;
        }
    }
}

__device__ __forceinline__ void load16_to_lds(const unsigned short* g,
                                              unsigned short* l) {
    __builtin_amdgcn_global_load_lds((gbl_void*)g, (lds_void*)l, 16, 0, 0);
}

// ---------------------------------------------------------------------------
// 256x128 bf16 GEMM: C[M][N] = A[M][K] * Bt[N][K]^T, BK=64 (48 KB LDS),
// 512 thr = 8 waves (4Mx2N), each wave 4x4 of 16x16x32 MFMA per sub-k.
// LDS XOR swizzle (phys chunk = logical ^ (row&7)); XCD-stripe block remap.
// Single-buffered 2-barrier loop; latency hidden by 2 blocks/CU residency.
// CASTA=1: A is fp32 (Afq for bz=0, Afk for bz=1), reg-staged with
//          v_cvt_pk_bf16_f32 (RTNE == f2b) + ds_write_b128.
// MODE 0: bf16 out, + bias (bias1 used when bz==1 -- merged l1/l2)
// MODE 1: bf16 out = exp(acc*scale), atomicAdd per-row sums into rowsum
// ---------------------------------------------------------------------------
template <int MODE, int CASTA>
__global__ __launch_bounds__(512, 4) void gemm256_kernel(
                               const unsigned short* __restrict__ A,
                               const unsigned short* __restrict__ Bt,
                               const float* __restrict__ bias0,
                               const float* __restrict__ bias1,
                               float* __restrict__ rowsum,
                               void* __restrict__ Cout,
                               int M, int N, int K,
                               float scale,
                               long sA, long sB, long sC,
                               const float* __restrict__ Afq,
                               const float* __restrict__ Afk) {
    __shared__ __align__(16) unsigned short As[256 * 64];  // 32 KB
    __shared__ __align__(16) unsigned short Bs[128 * 64];  // 16 KB

    // ---- XCD-aware tile remap (bijective) ----
    int bx, by, bz;
    {
        const int nx = gridDim.x;
        const int Rt = gridDim.y * gridDim.z;
        if ((Rt & 7) == 0) {
            int flat = ((int)blockIdx.z * gridDim.y + blockIdx.y) * nx + blockIdx.x;
            int rpx = Rt >> 3;
            int c = flat & 7;
            int j = flat >> 3;
            bx = j / rpx;
            int yg = c * rpx + (j - bx * rpx);
            bz = yg / gridDim.y;
            by = yg - bz * gridDim.y;
        } else {
            bx = blockIdx.x; by = blockIdx.y; bz = blockIdx.z;
        }
    }

    Bt += (long)bz * sB;

    const int t = threadIdx.x;
    const int lane = t & 63;
    const int wave = t >> 6;               // 0..7
    const int wm = wave >> 1, wn = wave & 1;  // 4M x 2N
    const int row0 = by * 256;
    const int col0 = bx * 128;

    // staging: lane l -> row group l>>3 (8 rows/issue), phys chunk l&7;
    // source chunk XOR'd so phys = logical ^ (row&7)
    const int rS = lane >> 3;
    const int kOffS = ((lane & 7) ^ rS) * 8;
    const unsigned short* gA[4];
    const float* fA[4];
    unsigned short* lA[4];
    const unsigned short* gB[2];
    unsigned short* lB[2];
#pragma unroll
    for (int i = 0; i < 4; i++) {
        const int rowl = wave * 32 + i * 8;
        lA[i] = As + rowl * 64;
        if (CASTA) {
            const float* Af = bz ? Afk : Afq;
            fA[i] = Af + (long)(row0 + rowl + rS) * K + kOffS;
        } else {
            gA[i] = A + (long)bz * sA + (long)(row0 + rowl + rS) * K + kOffS;
        }
    }
#pragma unroll
    for (int i = 0; i < 2; i++) {
        const int rowl = wave * 16 + i * 8;
        gB[i] = Bt + (long)(col0 + rowl + rS) * K + kOffS;
        lB[i] = Bs + rowl * 64;
    }

    const int lr = lane & 15;
    const int quad = lane >> 4;
    const int pc0 = (quad ^ (lr & 7)) * 8;
    const int pc1 = ((4 + quad) ^ (lr & 7)) * 8;

    f32x4 acc[4][4];
#pragma unroll
    for (int i = 0; i < 4; i++)
#pragma unroll
        for (int j = 0; j < 4; j++) acc[i][j] = f32x4{0.f, 0.f, 0.f, 0.f};

    for (int k0 = 0; k0 < K; k0 += 64) {
#pragma unroll
        for (int i = 0; i < 2; i++) load16_to_lds(gB[i] + k0, lB[i]);
        if (CASTA) {
            // reg-stage A: fp32 -> bf16 (RTNE cvt_pk) -> LDS, same layout
            // as the gload_lds path (base + lane*16B).
#pragma unroll
            for (int i = 0; i < 4; i++) {
                const float* s = fA[i] + k0;
                float4 x = *(const float4*)(s);
                float4 y = *(const float4*)(s + 4);
                unsigned w0, w1, w2, w3;
                asm("v_cvt_pk_bf16_f32 %0, %1, %2" : "=v"(w0) : "v"(x.x), "v"(x.y));
                asm("v_cvt_pk_bf16_f32 %0, %1, %2" : "=v"(w1) : "v"(x.z), "v"(x.w));
                asm("v_cvt_pk_bf16_f32 %0, %1, %2" : "=v"(w2) : "v"(y.x), "v"(y.y));
                asm("v_cvt_pk_bf16_f32 %0, %1, %2" : "=v"(w3) : "v"(y.z), "v"(y.w));
                *(u32x4*)(lA[i] + lane * 8) = u32x4{w0, w1, w2, w3};
            }
        } else {
#pragma unroll
            for (int i = 0; i < 4; i++) load16_to_lds(gA[i] + k0, lA[i]);
        }
        __syncthreads();

#pragma unroll
        for (int ks = 0; ks < 2; ks++) {
            const int pc = ks ? pc1 : pc0;
            bf16x8 a[4], b[4];
#pragma unroll
            for (int i = 0; i < 4; i++) {
                a[i] = __builtin_bit_cast(bf16x8,
                    *(const short8*)(As + (wm * 64 + i * 16 + lr) * 64 + pc));
                b[i] = __builtin_bit_cast(bf16x8,
                    *(const short8*)(Bs + (wn * 64 + i * 16 + lr) * 64 + pc));
            }
#pragma unroll
            for (int i = 0; i < 4; i++)
#pragma unroll
                for (int j = 0; j < 4; j++)
                    acc[i][j] = __builtin_amdgcn_mfma_f32_16x16x32_bf16(
                        a[i], b[j], acc[i][j], 0, 0, 0);
        }
        __syncthreads();
    }

    // ---- epilogue (C/D layout: col = lane&15, row = quad*4 + reg) ----
    const long cbase = (long)bz * sC;

    if (MODE == 0) {
        const float* bp = (bz && bias1) ? bias1 : bias0;
#pragma unroll
        for (int j = 0; j < 4; j++) {
            const int gcol = col0 + wn * 64 + j * 16 + lr;
            const float bv = bp[gcol];
#pragma unroll
            for (int i = 0; i < 4; i++) {
                const int growb = row0 + wm * 64 + i * 16 + quad * 4;
#pragma unroll
                for (int r = 0; r < 4; r++) {
                    float val = acc[i][j][r] * scale + bv;
                    ((unsigned short*)Cout)[cbase + (long)(growb + r) * N + gcol] = f2b(val);
                }
            }
        }
    } else {  // MODE == 1
        float psum[4][4];
#pragma unroll
        for (int i = 0; i < 4; i++)
#pragma unroll
            for (int r = 0; r < 4; r++) psum[i][r] = 0.f;
#pragma unroll
        for (int j = 0; j < 4; j++) {
            const int gcol = col0 + wn * 64 + j * 16 + lr;
#pragma unroll
            for (int i = 0; i < 4; i++) {
                const int growb = row0 + wm * 64 + i * 16 + quad * 4;
#pragma unroll
                for (int r = 0; r < 4; r++) {
                    float e = __expf(acc[i][j][r] * scale);
                    psum[i][r] += e;
                    ((unsigned short*)Cout)[cbase + (long)(growb + r) * N + gcol] = f2b(e);
                }
            }
        }
        // reduce across the 16 lr lanes (xor masks 1,2,4,8 keep quad bits)
#pragma unroll
        for (int i = 0; i < 4; i++)
#pragma unroll
            for (int r = 0; r < 4; r++) {
                float s = psum[i][r];
                s += __shfl_xor(s, 1);
                s += __shfl_xor(s, 2);
                s += __shfl_xor(s, 4);
                s += __shfl_xor(s, 8);
                if (lr == 0) {
                    const int grow = row0 + wm * 64 + i * 16 + quad * 4 + r;
                    atomicAdd(rowsum + (long)bz * M + grow, s);
                }
            }
    }
}

// ---------------------------------------------------------------------------
// Verbatim R4 128x128 engine -- used for the att GEMM (512 blocks = 2/CU).
// ---------------------------------------------------------------------------
template <int MODE>
__global__ void gemm128_kernel(const unsigned short* __restrict__ A,
                               const unsigned short* __restrict__ Bt,
                               float* __restrict__ rowsum,
                               void* __restrict__ Cout,
                               int M, int N, int K,
                               long sA, long sB, long sC) {
    __shared__ __align__(16) unsigned short As[128 * 64];
    __shared__ __align__(16) unsigned short Bs[128 * 64];

    int bx, by, bz;
    {
        const int nx = gridDim.x;
        const int Rt = gridDim.y * gridDim.z;
        if ((Rt & 7) == 0) {
            int flat = ((int)blockIdx.z * gridDim.y + blockIdx.y) * nx + blockIdx.x;
            int rpx = Rt >> 3;
            int c = flat & 7;
            int j = flat >> 3;
            bx = j / rpx;
            int yg = c * rpx + (j - bx * rpx);
            bz = yg / gridDim.y;
            by = yg - bz * gridDim.y;
        } else {
            bx = blockIdx.x; by = blockIdx.y; bz = blockIdx.z;
        }
    }

    A  += (long)bz * sA;
    Bt += (long)bz * sB;

    const int t = threadIdx.x;
    const int lane = t & 63;
    const int wave = t >> 6;
    const int wm = wave >> 1, wn = wave & 1;
    const int row0 = by * 128;
    const int col0 = bx * 128;

    const int rS = lane >> 3;
    const int kOffS = ((lane & 7) ^ rS) * 8;
    const unsigned short* gA[4];
    const unsigned short* gB[4];
    unsigned short* lA[4];
    unsigned short* lB[4];
#pragma unroll
    for (int i = 0; i < 4; i++) {
        const int rowl = i * 32 + wave * 8 + rS;
        const int ldsrow = i * 32 + wave * 8;
        gA[i] = A  + (long)(row0 + rowl) * K + kOffS;
        gB[i] = Bt + (long)(col0 + rowl) * K + kOffS;
        lA[i] = As + ldsrow * 64;
        lB[i] = Bs + ldsrow * 64;
    }

    const int lr = lane & 15;
    const int quad = lane >> 4;
    const int pc0 = (quad ^ (lr & 7)) * 8;
    const int pc1 = ((4 + quad) ^ (lr & 7)) * 8;

    f32x4 acc[4][4];
#pragma unroll
    for (int i = 0; i < 4; i++)
#pragma unroll
        for (int j = 0; j < 4; j++) acc[i][j] = f32x4{0.f, 0.f, 0.f, 0.f};

    for (int k0 = 0; k0 < K; k0 += 64) {
#pragma unroll
        for (int i = 0; i < 4; i++) {
            load16_to_lds(gA[i] + k0, lA[i]);
            load16_to_lds(gB[i] + k0, lB[i]);
        }
        __syncthreads();

#pragma unroll
        for (int ks = 0; ks < 2; ks++) {
            const int pc = ks ? pc1 : pc0;
            bf16x8 a[4], b[4];
#pragma unroll
            for (int i = 0; i < 4; i++) {
                a[i] = __builtin_bit_cast(bf16x8,
                    *(const short8*)(As + (wm * 64 + i * 16 + lr) * 64 + pc));
                b[i] = __builtin_bit_cast(bf16x8,
                    *(const short8*)(Bs + (wn * 64 + i * 16 + lr) * 64 + pc));
            }
#pragma unroll
            for (int i = 0; i < 4; i++)
#pragma unroll
                for (int j = 0; j < 4; j++)
                    acc[i][j] = __builtin_amdgcn_mfma_f32_16x16x32_bf16(
                        a[i], b[j], acc[i][j], 0, 0, 0);
        }
        __syncthreads();
    }

    const long cbase = (long)bz * sC;

    if (MODE == 2) {
#pragma unroll
        for (int i = 0; i < 4; i++) {
            const int growb = row0 + wm * 64 + i * 16 + quad * 4;
#pragma unroll
            for (int r = 0; r < 4; r++) {
                const float inv = 1.0f / rowsum[(long)bz * M + growb + r];
#pragma unroll
                for (int j = 0; j < 4; j++) {
                    const int gcol = col0 + wn * 64 + j * 16 + lr;
                    ((float*)Cout)[cbase + (long)(growb + r) * N + gcol] =
                        acc[i][j][r] * inv;
                }
            }
        }
    }
}

// ---------------------------------------------------------------------------
extern "C" void kernel_launch(void* const* d_in, const int* in_sizes, int n_in,
                              void* d_out, int out_size, void* d_ws, size_t ws_size,
                              hipStream_t stream) {
    const float* q   = (const float*)d_in[0];
    const float* k   = (const float*)d_in[1];
    const float* v   = (const float*)d_in[2];
    const float* W1w = (const float*)d_in[3];
    const float* W1b = (const float*)d_in[4];
    const float* W2w = (const float*)d_in[5];
    const float* W2b = (const float*)d_in[6];
    float* out = (float*)d_out;

    const int B = 4, SQ = 2048, SK = 2048, D = 1024, U = 1024;
    char* ws = (char*)d_ws;
    const size_t MB = 1024 * 1024;
    unsigned short* vT  = (unsigned short*)(ws + 32 * MB);  // 16 MB [B][D][SK]
    unsigned short* W1t = (unsigned short*)(ws + 48 * MB);  // 2 MB  [U][D]
    unsigned short* W2t = (unsigned short*)(ws + 50 * MB);  // 2 MB
    unsigned short* l1  = (unsigned short*)(ws + 52 * MB);  // 16 MB [B*SQ][U]
    unsigned short* l2  = (unsigned short*)(ws + 68 * MB);  // 16 MB
    unsigned short* sc  = (unsigned short*)(ws + 0);        // 32 MB [B][SQ][SK]

    // rowsum: fresh slot at 84 MB, zeroed inside prep (no memset dispatch);
    // fallback: W2t slot + memset between l1l2 and score.
    float* rowsum;
    bool prep_zeroes_rowsum;
    if (ws_size >= 85 * MB) {
        rowsum = (float*)(ws + 84 * MB);
        prep_zeroes_rowsum = true;
    } else {
        rowsum = (float*)(ws + 50 * MB);
        prep_zeroes_rowsum = false;
    }

    // 1: prep (v/W transposes + rowsum zero) -- q/k casts in-GEMM
    prep_kernel<<<dim3(64, 8, 6), 256, 0, stream>>>(
        v, W1w, W2w, vT, W1t, W2t,
        prep_zeroes_rowsum ? rowsum : nullptr);
    // 2: merged l1 = q@W1+b1 (bz=0), l2 = k@W2+b2 (bz=1); A cast in-flight
    gemm256_kernel<0, 1><<<dim3(U / 128, (B * SQ) / 256, 2), 512, 0, stream>>>(
        nullptr, W1t, W1b, W2b, nullptr, l1, B * SQ, U, D, 1.0f,
        0, (long)1024 * 1024, (long)8 * 1024 * 1024, q, k);
    // 3 (fallback only): zero rowsum in the W2t slot after l1l2 read it
    if (!prep_zeroes_rowsum)
        hipMemsetAsync(rowsum, 0, (size_t)B * SQ * sizeof(float), stream);
    // 4: sc = exp(l1 @ l2^T / sqrt(SK)) bf16 + rowsum atomics
    const float invs = 1.0f / sqrtf((float)SK);
    gemm256_kernel<1, 0><<<dim3(SK / 128, SQ / 256, B), 512, 0, stream>>>(
        l1, l2, nullptr, nullptr, rowsum, sc, SQ, SK, U, invs,
        (long)SQ * U, (long)SK * U, (long)SQ * SK, nullptr, nullptr);
    // 5: att = (sc @ vT^T) / rowsum[row]  (fp32 out) -- proven 128^2 engine
    gemm128_kernel<2><<<dim3(D / 128, SQ / 128, B), 256, 0, stream>>>(
        sc, vT, rowsum, out, SQ, D, SK,
        (long)SQ * SK, (long)D * SK, (long)SQ * D);
}